// Round 2
// baseline (505.805 us; speedup 1.0000x reference)
//
#include <hip/hip_runtime.h>

#define NC 19
#define HW_ (512 * 1024)
#define NPIX (2 * HW_)
#define THRESH 0.9f
#define IGNORE_L 255
#define BLK 256
#define NBLOCKS (NPIX / 2 / BLK)   // 2 pixels/thread -> 2048 blocks = 32 waves/CU

// Fused: softmax(19) + weight/renorm + wp store + histogram + SE partial,
// with last-block finalize (ticket) -> out[0]. One memset node + one kernel.
__global__ __launch_bounds__(256) void calib_fused(
    const float* __restrict__ pred,
    const float* __restrict__ weight,
    const int*   __restrict__ label,
    float* __restrict__ wp_out,     // == d_out + 1 (4B-aligned only)
    int*   __restrict__ g_hist,
    float* __restrict__ g_se,
    unsigned int* __restrict__ g_ticket,
    float* __restrict__ out)
{
    __shared__ int   hist[NC];
    __shared__ float wsum[4];

    const int tid = threadIdx.x;
    if (tid < NC) hist[tid] = 0;
    __syncthreads();

    const int gid = blockIdx.x * BLK + tid;      // one work item = 2 pixels
    const int b   = gid / (HW_ / 2);             // batch 0/1 (pow2 shift)
    const int hw  = (gid - b * (HW_ / 2)) * 2;

    const float* p0 = pred + (size_t)b * NC * HW_ + hw;

    float x[NC][2];
#pragma unroll
    for (int c = 0; c < NC; ++c) {
        float2 v = *reinterpret_cast<const float2*>(p0 + (size_t)c * HW_);
        x[c][0] = v.x; x[c][1] = v.y;
    }
    int2 lv = *reinterpret_cast<const int2*>(label + (size_t)b * HW_ + hw);
    const int lbls[2] = { lv.x, lv.y };

    // no max-subtraction: |logit| <= ~40 << 88, exp cannot overflow fp32
    float den[2] = {0.f, 0.f};
#pragma unroll
    for (int c = 0; c < NC; ++c) {
        const float w = weight[c];               // uniform addr -> scalar load
#pragma unroll
        for (int j = 0; j < 2; ++j) {
            float e = w * __expf(x[c][j]);
            x[c][j] = e;
            den[j] += e;
        }
    }
    const float rden[2] = { 1.f / den[0], 1.f / den[1] };

    float sumsq[2] = {0.f, 0.f}, wl[2] = {0.f, 0.f};
    int   cls[2]   = {-1, -1};

    float* o0 = wp_out + (size_t)b * NC * HW_ + hw;
#pragma unroll
    for (int c = 0; c < NC; ++c) {
#pragma unroll
        for (int j = 0; j < 2; ++j) {
            float wp = x[c][j] * rden[j];
            o0[(size_t)c * HW_ + j] = wp;        // dword stores (dest 4B-aligned)
            sumsq[j] += wp * wp;
            if (wp > THRESH)  cls[j] = c;        // at most one class > 0.9
            if (lbls[j] == c) wl[j]  = wp;
        }
    }

    float se = 0.f;
#pragma unroll
    for (int j = 0; j < 2; ++j) {
        float s = (lbls[j] >= 0 && lbls[j] < NC) ? (sumsq[j] - 2.f * wl[j] + 1.f)
                                                 : sumsq[j];
        if (lbls[j] == IGNORE_L) s = 0.f;
        se += s;
        if (cls[j] >= 0) atomicAdd(&hist[cls[j]], 1);
    }

#pragma unroll
    for (int off = 32; off > 0; off >>= 1) se += __shfl_down(se, off, 64);
    if ((tid & 63) == 0) wsum[tid >> 6] = se;
    __syncthreads();

    if (tid == 0) {
        // thread 0 owns ALL of this block's global accumulator traffic so the
        // acq_rel ticket below orders it (release sequence across blocks).
        atomicAdd(g_se, wsum[0] + wsum[1] + wsum[2] + wsum[3]);
#pragma unroll
        for (int i = 0; i < NC; ++i) {
            int h = hist[i];
            if (h) atomicAdd(&g_hist[i], h);
        }
        unsigned int t = __hip_atomic_fetch_add(g_ticket, 1u,
                             __ATOMIC_ACQ_REL, __HIP_MEMORY_SCOPE_AGENT);
        if (t == (unsigned int)(NBLOCKS - 1)) {
            // last block: finalize
            const float prior[NC] = {32.07f, 5.71f, 20.7f, 0.564f, 0.761f,
                                     1.054f, 0.1696f, 0.5014f, 13.4993f,
                                     0.8981f, 3.6445f, 1.1458f, 0.1393f, 6.0f,
                                     0.2949f, 0.1954f, 0.2341f, 0.0818f, 0.3917f};
            float psum = 0.f, total = 0.f, h[NC];
#pragma unroll
            for (int i = 0; i < NC; ++i) {
                h[i] = (float)__hip_atomic_load(&g_hist[i], __ATOMIC_RELAXED,
                                                __HIP_MEMORY_SCOPE_AGENT);
                psum += prior[i]; total += h[i];
            }
            float rl = 0.f;
#pragma unroll
            for (int i = 0; i < NC; ++i) {
                float d = h[i] / total - prior[i] / psum;
                rl += d * d;
            }
            float sse = __hip_atomic_load(g_se, __ATOMIC_RELAXED,
                                          __HIP_MEMORY_SCOPE_AGENT);
            out[0] = rl + 0.05f * (sse * (1.0f / (float)NPIX));
        }
    }
}

extern "C" void kernel_launch(void* const* d_in, const int* in_sizes, int n_in,
                              void* d_out, int out_size, void* d_ws, size_t ws_size,
                              hipStream_t stream) {
    const float* pred   = (const float*)d_in[0];
    const float* weight = (const float*)d_in[1];
    const int*   label  = (const int*)d_in[2];
    float* out = (float*)d_out;
    int*          g_hist   = (int*)d_ws;
    float*        g_se     = (float*)((char*)d_ws + 128);
    unsigned int* g_ticket = (unsigned int*)((char*)d_ws + 192);

    // d_ws is re-poisoned to 0xAA before every launch -> zero accumulators.
    hipMemsetAsync(d_ws, 0, 256, stream);

    calib_fused<<<NBLOCKS, BLK, 0, stream>>>(pred, weight, label,
                                             out + 1, g_hist, g_se, g_ticket, out);
}